// Round 5
// baseline (318.874 us; speedup 1.0000x reference)
//
#include <hip/hip_runtime.h>
#include <hip/hip_bf16.h>

#define B_  16
#define S_  4096
#define DIN 512
#define DH  512

typedef _Float16 f16x8 __attribute__((ext_vector_type(8)));
typedef float    f32x4 __attribute__((ext_vector_type(4)));

// ---------------- ws layout (bytes) ----------------
// W16     : [DH][DIN] fp16      @ 0        (524288)
// addv    : [B_][DH]  f32       @ 524288   (32768)   = input@W_in.T + b_in + b_ctx
// scores  : [B_][S_]  f32       @ 557056   (262144)
// maskflag: int                 @ 851968   (4)       1 = mask is byte-per-elem

__device__ __forceinline__ float fast_tanh(float x) {
    float e = __expf(2.f * x);
    return 1.f - 2.f * __builtin_amdgcn_rcpf(e + 1.f);
}

__device__ __forceinline__ void gload_lds16(const void* g, void* l) {
    __builtin_amdgcn_global_load_lds(
        (const __attribute__((address_space(1))) void*)g,
        (__attribute__((address_space(3))) void*)l, 16, 0, 0);
}

// ---------------- prep ----------------
__global__ void prep_kernel(const float* __restrict__ input,
                            const float* __restrict__ W_in,
                            const float* __restrict__ b_in,
                            const float* __restrict__ W_ctx,
                            const float* __restrict__ b_ctx,
                            const void*  __restrict__ mask,
                            _Float16* __restrict__ W16,
                            float* __restrict__ addv,
                            int* __restrict__ maskflag) {
    int blk = blockIdx.x;
    int tid = threadIdx.x;
    if (blk < 256) {
        // W_ctx fp32 -> fp16 : 262144 elems, 4/thread
        int base = blk * 1024 + tid * 4;
        float4 wv = *(const float4*)(W_ctx + base);
        union { _Float16 f[4]; ushort4 u; } cv;
        cv.f[0] = (_Float16)wv.x; cv.f[1] = (_Float16)wv.y;
        cv.f[2] = (_Float16)wv.z; cv.f[3] = (_Float16)wv.w;
        *(ushort4*)(W16 + base) = cv.u;
    } else if (blk < 288) {
        int t = blk - 256;
        int b = t >> 1;
        int h = ((t & 1) << 8) + tid;
        __shared__ float inrow[DIN];
        inrow[tid]       = input[b * DIN + tid];
        inrow[tid + 256] = input[b * DIN + tid + 256];
        __syncthreads();
        const float* wr = W_in + (size_t)h * DIN;
        float acc = 0.f;
        for (int k = 0; k < DIN; k += 4) {
            float4 w4 = *(const float4*)(wr + k);
            acc += w4.x * inrow[k] + w4.y * inrow[k + 1]
                 + w4.z * inrow[k + 2] + w4.w * inrow[k + 3];
        }
        addv[b * DH + h] = acc + b_in[h] + b_ctx[h];
    } else {
        // mask dtype detect, vectorized: int32 bools are 0/1 (upper bytes 0).
        const uint4* m4 = (const uint4*)mask;
        unsigned int orw = 0;
#pragma unroll
        for (int it = 0; it < 16; ++it) {
            uint4 w = m4[it * 256 + tid];
            orw |= (w.x | w.y | w.z | w.w);
        }
        int found = ((orw & 0xFFFFFF00u) != 0) ? 1 : 0;
        __shared__ int f;
        if (tid == 0) f = 0;
        __syncthreads();
        if (found) atomicOr(&f, 1);
        __syncthreads();
        if (tid == 0) maskflag[0] = f;
    }
}

// ---------------- score: v . tanh(addv + context@W16^T), masked ----------------
// 512-thread blocks (8 waves), grid 256 = 1 block/CU. Each block: 256 s-rows
// (wave w owns rows s0+w*32..+32, 2 m-tiles, A in regs full-K). 8 waves share
// ONE B stream: 16 chunks x 32KB, double-buffered, staged w/ global_load_lds
// w16 (wave stages 4KB/chunk). Barriers/unit-work halved vs r4; B L2 traffic
// halved. addv/v preloaded to LDS so barriers drain only the B stage.

__global__ __launch_bounds__(512, 2)
void score_kernel(const float* __restrict__ context,
                  const _Float16* __restrict__ W16,
                  const float* __restrict__ addv,
                  const float* __restrict__ v,
                  const void* __restrict__ mask,
                  const int* __restrict__ maskflag,
                  float* __restrict__ scores) {
    __shared__ _Float16 Bs[2][16384];   // 2 x 32KB
    __shared__ float avS[DH];
    __shared__ float vvS[DH];

    const int tid  = threadIdx.x;
    const int wave = tid >> 6;
    const int lane = tid & 63;
    const int l15  = lane & 15;
    const int q    = lane >> 4;
    const int b    = blockIdx.x >> 4;
    const int s0   = (blockIdx.x & 15) * 256;

    // preload addv, v into LDS (visible after first chunk barrier)
    avS[tid] = addv[b * DH + tid];
    vvS[tid] = v[tid];

    // ---- A fragments (registers, full K): rows s0+wave*32+t*16+l15 ----
    f16x8 a[2][16];
#pragma unroll
    for (int t = 0; t < 2; ++t) {
        const float* arow = context +
            ((size_t)b * S_ + s0 + wave * 32 + t * 16 + l15) * DIN + q * 8;
#pragma unroll
        for (int kc = 0; kc < 16; ++kc) {
            float4 x0 = *(const float4*)(arow + kc * 32);
            float4 x1 = *(const float4*)(arow + kc * 32 + 4);
            f16x8 tt;
            tt[0] = (_Float16)x0.x; tt[1] = (_Float16)x0.y;
            tt[2] = (_Float16)x0.z; tt[3] = (_Float16)x0.w;
            tt[4] = (_Float16)x1.x; tt[5] = (_Float16)x1.y;
            tt[6] = (_Float16)x1.z; tt[7] = (_Float16)x1.w;
            a[t][kc] = tt;
        }
    }

    float rowsum[2][4] = {{0.f,0.f,0.f,0.f},{0.f,0.f,0.f,0.f}};

    // chunk c (0..15): win = c>>1, khalf = c&1. 32 stage instrs/chunk, 8 waves
    // -> 4 each; instr id = kl*4+j covers (k-sub kl, n-tile j); lane L lands at
    // LDS halves [id*512 + L*8). Read: Bs[buf][(kl*4+j)*512 + q*128 + l15*8]
    // -> 2 lanes/bank (free).
#define STAGE_CHUNK(c_)                                                        \
    {                                                                          \
        int win_s = (c_) >> 1, kh_s = (c_) & 1;                                \
        _Float16* dst = &Bs[(c_) & 1][0];                                      \
        _Pragma("unroll")                                                      \
        for (int u = 0; u < 4; ++u) {                                          \
            int id = wave * 4 + u;                                             \
            int kl = id >> 2, j = id & 3;                                      \
            const _Float16* g = W16 +                                          \
                (size_t)(win_s * 64 + j * 16 + l15) * DIN +                    \
                kh_s * 256 + kl * 32 + q * 8;                                  \
            gload_lds16(g, dst + id * 512);                                    \
        }                                                                      \
    }

    STAGE_CHUNK(0);

    for (int win = 0; win < 8; ++win) {
        f32x4 acc[2][4];
#pragma unroll
        for (int t = 0; t < 2; ++t)
#pragma unroll
            for (int j = 0; j < 4; ++j) acc[t][j] = (f32x4){0.f,0.f,0.f,0.f};

#pragma unroll
        for (int kh = 0; kh < 2; ++kh) {
            int c = win * 2 + kh;
            __syncthreads();            // drains stage(c); buf(c-1) reads done
            if (c + 1 < 16) STAGE_CHUNK(c + 1);
            const _Float16* Bbuf = &Bs[c & 1][0];
#pragma unroll
            for (int kl = 0; kl < 8; ++kl) {
                int kc = kh * 8 + kl;
                f16x8 bf0 = *(const f16x8*)&Bbuf[(kl * 4 + 0) * 512 + q * 128 + l15 * 8];
                f16x8 bf1 = *(const f16x8*)&Bbuf[(kl * 4 + 1) * 512 + q * 128 + l15 * 8];
                f16x8 bf2 = *(const f16x8*)&Bbuf[(kl * 4 + 2) * 512 + q * 128 + l15 * 8];
                f16x8 bf3 = *(const f16x8*)&Bbuf[(kl * 4 + 3) * 512 + q * 128 + l15 * 8];
                acc[0][0] = __builtin_amdgcn_mfma_f32_16x16x32_f16(a[0][kc], bf0, acc[0][0], 0, 0, 0);
                acc[1][0] = __builtin_amdgcn_mfma_f32_16x16x32_f16(a[1][kc], bf0, acc[1][0], 0, 0, 0);
                acc[0][1] = __builtin_amdgcn_mfma_f32_16x16x32_f16(a[0][kc], bf1, acc[0][1], 0, 0, 0);
                acc[1][1] = __builtin_amdgcn_mfma_f32_16x16x32_f16(a[1][kc], bf1, acc[1][1], 0, 0, 0);
                acc[0][2] = __builtin_amdgcn_mfma_f32_16x16x32_f16(a[0][kc], bf2, acc[0][2], 0, 0, 0);
                acc[1][2] = __builtin_amdgcn_mfma_f32_16x16x32_f16(a[1][kc], bf2, acc[1][2], 0, 0, 0);
                acc[0][3] = __builtin_amdgcn_mfma_f32_16x16x32_f16(a[0][kc], bf3, acc[0][3], 0, 0, 0);
                acc[1][3] = __builtin_amdgcn_mfma_f32_16x16x32_f16(a[1][kc], bf3, acc[1][3], 0, 0, 0);
            }
        }
        // window epilogue — av/vv from LDS (no global traffic at barriers)
#pragma unroll
        for (int j = 0; j < 4; ++j) {
            int n = win * 64 + j * 16 + l15;
            float av = avS[n];
            float vv = vvS[n];
#pragma unroll
            for (int t = 0; t < 2; ++t)
#pragma unroll
                for (int r = 0; r < 4; ++r)
                    rowsum[t][r] += vv * fast_tanh(acc[t][j][r] + av);
        }
    }

    // ---- reduce over l15, write scores with mask ----
    int isByte = maskflag[0];
#pragma unroll
    for (int t = 0; t < 2; ++t)
#pragma unroll
        for (int r = 0; r < 4; ++r) {
            float s = rowsum[t][r];
            s += __shfl_xor(s, 1, 16);
            s += __shfl_xor(s, 2, 16);
            s += __shfl_xor(s, 4, 16);
            s += __shfl_xor(s, 8, 16);
            if (l15 == 0) {
                int srow = s0 + wave * 32 + t * 16 + q * 4 + r;  // C row = q*4+r
                int idx = b * S_ + srow;
                int msk = isByte ? (int)((const unsigned char*)mask)[idx]
                                 : ((const int*)mask)[idx];
                scores[idx] = msk ? -__builtin_inff() : s;
            }
        }
}

// ---------------- fused softmax + select + weighted-sum + project ----------------
// One block per batch row. attn>1e-9 selects ~50-150 rows (peaked softmax);
// dropped mass <= 4096e-9 -> err ~1e-5. Row loop unrolled x4 (8 loads in
// flight) to break the serial-latency chain.
__global__ __launch_bounds__(256)
void final_kernel(const float* __restrict__ scores,
                  const float* __restrict__ context,
                  const float* __restrict__ W_ctx,
                  const float* __restrict__ b_ctx,
                  float* __restrict__ attn,
                  float* __restrict__ hidden) {
    __shared__ float rbuf[4];
    __shared__ float wsumS[DIN];
    __shared__ int   selIdx[S_];
    __shared__ float selW[S_];
    __shared__ int   selCount;

    int b = blockIdx.x, tid = threadIdx.x;
    int wv = tid >> 6, ln = tid & 63;
    const float* sr = scores + b * S_;

    float mx = -__builtin_inff();
    for (int s = tid; s < S_; s += 256) mx = fmaxf(mx, sr[s]);
    for (int o = 1; o < 64; o <<= 1) mx = fmaxf(mx, __shfl_xor(mx, o, 64));
    if (ln == 0) rbuf[wv] = mx;
    __syncthreads();
    mx = fmaxf(fmaxf(rbuf[0], rbuf[1]), fmaxf(rbuf[2], rbuf[3]));
    __syncthreads();

    float sum = 0.f;
    for (int s = tid; s < S_; s += 256) sum += __expf(sr[s] - mx);
    for (int o = 1; o < 64; o <<= 1) sum += __shfl_xor(sum, o, 64);
    if (ln == 0) rbuf[wv] = sum;
    if (tid == 0) selCount = 0;
    __syncthreads();
    sum = rbuf[0] + rbuf[1] + rbuf[2] + rbuf[3];
    float inv = 1.f / sum;

    float* ab = attn + b * S_;
    for (int s = tid; s < S_; s += 256) {
        float p = __expf(sr[s] - mx) * inv;
        ab[s] = p;
        if (p > 1e-9f) {
            int k = atomicAdd(&selCount, 1);
            selIdx[k] = s;
            selW[k]  = p;
        }
    }
    __syncthreads();

    int cnt = selCount;
    const float* cb = context + (size_t)b * S_ * DIN;
    float a00 = 0.f, a01 = 0.f, a10 = 0.f, a11 = 0.f;
    float a20 = 0.f, a21 = 0.f, a30 = 0.f, a31 = 0.f;
    int i = 0;
    for (; i + 4 <= cnt; i += 4) {
        const float* c0 = cb + (size_t)selIdx[i]     * DIN;
        const float* c1 = cb + (size_t)selIdx[i + 1] * DIN;
        const float* c2 = cb + (size_t)selIdx[i + 2] * DIN;
        const float* c3 = cb + (size_t)selIdx[i + 3] * DIN;
        float w0 = selW[i], w1 = selW[i + 1], w2 = selW[i + 2], w3 = selW[i + 3];
        float x00 = c0[tid], x01 = c0[tid + 256];
        float x10 = c1[tid], x11 = c1[tid + 256];
        float x20 = c2[tid], x21 = c2[tid + 256];
        float x30 = c3[tid], x31 = c3[tid + 256];
        a00 += w0 * x00; a01 += w0 * x01;
        a10 += w1 * x10; a11 += w1 * x11;
        a20 += w2 * x20; a21 += w2 * x21;
        a30 += w3 * x30; a31 += w3 * x31;
    }
    float acc0 = (a00 + a10) + (a20 + a30);
    float acc1 = (a01 + a11) + (a21 + a31);
    for (; i < cnt; ++i) {
        int s = selIdx[i];
        float w = selW[i];
        const float* cr = cb + (size_t)s * DIN;
        acc0 += w * cr[tid];
        acc1 += w * cr[tid + 256];
    }
    wsumS[tid]       = acc0;
    wsumS[tid + 256] = acc1;
    __syncthreads();

    // hidden[b][h] = W_ctx[h,:] . wsum + b_ctx[h]  (2 h per thread)
#pragma unroll
    for (int hh = 0; hh < 2; ++hh) {
        int h = tid + hh * 256;
        const float* wr = W_ctx + (size_t)h * DIN;
        float acc = 0.f;
        for (int k = 0; k < DIN; k += 4) {
            float4 w4 = *(const float4*)(wr + k);
            acc += w4.x * wsumS[k] + w4.y * wsumS[k + 1]
                 + w4.z * wsumS[k + 2] + w4.w * wsumS[k + 3];
        }
        hidden[b * DH + h] = acc + b_ctx[h];
    }
}

extern "C" void kernel_launch(void* const* d_in, const int* in_sizes, int n_in,
                              void* d_out, int out_size, void* d_ws, size_t ws_size,
                              hipStream_t stream) {
    const float* input   = (const float*)d_in[0];
    const float* context = (const float*)d_in[1];
    const void*  mask    = d_in[2];
    const float* W_in    = (const float*)d_in[3];
    const float* b_in    = (const float*)d_in[4];
    const float* W_ctx   = (const float*)d_in[5];
    const float* b_ctx   = (const float*)d_in[6];
    const float* v       = (const float*)d_in[7];

    char* ws = (char*)d_ws;
    _Float16* W16   = (_Float16*)ws;
    float* addv     = (float*)(ws + 524288);
    float* scores   = (float*)(ws + 557056);
    int*   maskflag = (int*)(ws + 851968);

    float* hidden = (float*)d_out;                  // [16,512]
    float* attn   = (float*)d_out + B_ * DH;        // [16,4096]

    prep_kernel<<<289, 256, 0, stream>>>(input, W_in, b_in, W_ctx, b_ctx, mask,
                                         W16, addv, maskflag);
    score_kernel<<<256, 512, 0, stream>>>(context, W16, addv, v,
                                          mask, maskflag, scores);
    final_kernel<<<B_, 256, 0, stream>>>(scores, context, W_ctx, b_ctx,
                                         attn, hidden);
}

// Round 6
// 298.570 us; speedup vs baseline: 1.0680x; 1.0680x over previous
//
#include <hip/hip_runtime.h>
#include <hip/hip_bf16.h>

#define B_  16
#define S_  4096
#define DIN 512
#define DH  512

typedef _Float16 f16x8 __attribute__((ext_vector_type(8)));
typedef float    f32x4 __attribute__((ext_vector_type(4)));

// ---------------- ws layout (bytes) ----------------
// W16     : [DH][DIN] fp16      @ 0        (524288)
// addv    : [B_][DH]  f32       @ 524288   (32768)   = input@W_in.T + b_in + b_ctx
// scores  : [B_][S_]  f32       @ 557056   (262144)  zeroed in prep, atomicAdd by score
// wsum    : [B_][DIN] f32       @ 819200   (32768)   zeroed in prep, atomicAdd by attnwsum
// maskflag: int                 @ 851968   (4)
// stats   : [B_][2]   f32       @ 852096   (128)     {max, 1/sum}

__device__ __forceinline__ float fast_tanh(float x) {
    float e = __expf(2.f * x);
    return 1.f - 2.f * __builtin_amdgcn_rcpf(e + 1.f);
}

__device__ __forceinline__ void gload_lds16(const void* g, void* l) {
    __builtin_amdgcn_global_load_lds(
        (const __attribute__((address_space(1))) void*)g,
        (__attribute__((address_space(3))) void*)l, 16, 0, 0);
}

__device__ __forceinline__ int mask_at(const void* mask, int isByte, int idx) {
    return isByte ? (int)((const unsigned char*)mask)[idx]
                  : ((const int*)mask)[idx];
}

// ---------------- prep ----------------
__global__ void prep_kernel(const float* __restrict__ input,
                            const float* __restrict__ W_in,
                            const float* __restrict__ b_in,
                            const float* __restrict__ W_ctx,
                            const float* __restrict__ b_ctx,
                            const void*  __restrict__ mask,
                            _Float16* __restrict__ W16,
                            float* __restrict__ addv,
                            float* __restrict__ zeroRegion,   // scores..wsum, 270336 floats
                            int* __restrict__ maskflag) {
    int blk = blockIdx.x;
    int tid = threadIdx.x;
    if (blk < 256) {
        // W_ctx fp32 -> fp16 : 262144 elems, 4/thread
        int base = blk * 1024 + tid * 4;
        float4 wv = *(const float4*)(W_ctx + base);
        union { _Float16 f[4]; ushort4 u; } cv;
        cv.f[0] = (_Float16)wv.x; cv.f[1] = (_Float16)wv.y;
        cv.f[2] = (_Float16)wv.z; cv.f[3] = (_Float16)wv.w;
        *(ushort4*)(W16 + base) = cv.u;
    } else if (blk < 288) {
        int t = blk - 256;
        int b = t >> 1;
        int h = ((t & 1) << 8) + tid;
        __shared__ float inrow[DIN];
        inrow[tid]       = input[b * DIN + tid];
        inrow[tid + 256] = input[b * DIN + tid + 256];
        __syncthreads();
        const float* wr = W_in + (size_t)h * DIN;
        float acc = 0.f;
        for (int k = 0; k < DIN; k += 4) {
            float4 w4 = *(const float4*)(wr + k);
            acc += w4.x * inrow[k] + w4.y * inrow[k + 1]
                 + w4.z * inrow[k + 2] + w4.w * inrow[k + 3];
        }
        addv[b * DH + h] = acc + b_in[h] + b_ctx[h];
    } else if (blk == 288) {
        // mask dtype detect, vectorized: int32 bools are 0/1 (upper bytes 0).
        const uint4* m4 = (const uint4*)mask;
        unsigned int orw = 0;
#pragma unroll
        for (int it = 0; it < 16; ++it) {
            uint4 w = m4[it * 256 + tid];
            orw |= (w.x | w.y | w.z | w.w);
        }
        int found = ((orw & 0xFFFFFF00u) != 0) ? 1 : 0;
        __shared__ int f;
        if (tid == 0) f = 0;
        __syncthreads();
        if (found) atomicOr(&f, 1);
        __syncthreads();
        if (tid == 0) maskflag[0] = f;
    } else {
        // zero scores (262144) + wsum (8192): 270336 floats = 66 blocks*256*16
        int base = (blk - 289) * 4096;
#pragma unroll
        for (int it = 0; it < 16; ++it)
            zeroRegion[base + it * 256 + tid] = 0.f;
    }
}

// ---------------- score GEMM: partial rowsum of v.tanh(addv + ctx@W16^T) ----
// m97-style: both operands via LDS, BK=32 (one MFMA K-step), double-buffered.
// Block: 512 thr (8 waves), tile 128 s x 256 n. Wave (sg,ng): 32s x 128n ->
// acc[2][8] (64 VGPR). Grid: 16 b x 32 st x 2 nt = 1024 blocks. LDS 64KB ->
// 2 blocks/CU; regs <=128 -> 16 waves/CU. Epilogue: tanh.v reduce over the
// n-half, atomicAdd partial rowsums into zeroed scores (2 adds per row).
__global__ __launch_bounds__(512, 4)
void score_kernel(const float* __restrict__ context,
                  const _Float16* __restrict__ W16,
                  const float* __restrict__ addv,
                  const float* __restrict__ v,
                  float* __restrict__ scores) {
    __shared__ float    As[2][4096];   // 16KB per buf: 8 m-tiles x 512 floats
    __shared__ _Float16 Bs[2][8192];   // 16KB per buf: 16 n-tiles x 512 halves

    const int tid  = threadIdx.x;
    const int wave = tid >> 6;
    const int lane = tid & 63;
    const int l15  = lane & 15;
    const int q    = lane >> 4;
    const int sg   = wave >> 1;        // 0..3 : s-group (32 rows)
    const int ng   = wave & 1;         // 0..1 : n-group (128 cols)

    const int b  = blockIdx.x >> 6;
    const int st = (blockIdx.x & 63) >> 1;
    const int nt = blockIdx.x & 1;
    const int s0 = st * 128;
    const int n0 = nt * 256;

    const float* ctxA = context + ((size_t)b * S_ + s0) * DIN;

    // stage chunk kc into buf: 32 instrs (A: id<16 -> (jm,p); B: id>=16 -> jn)
    // A layout: tile jm floats [jm*512): instr(jm,p) lane L -> row jm*16+l15,
    //   k kc*32+q*8+p*4, lands at jm*512+p*256+L*4. Frag float4s at
    //   jm*512 + p*256 + lane*4.
    // B layout: tile jn halves [jn*512): lane L -> row n0+jn*16+l15,
    //   k kc*32+q*8, lands at L*8 halves. Frag b128 at jn*512+q*128+l15*8.
#define STAGE(kc_, buf_)                                                       \
    {                                                                          \
        _Pragma("unroll")                                                      \
        for (int u = 0; u < 4; ++u) {                                          \
            int id = wave * 4 + u;                                             \
            if (id < 16) {                                                     \
                int jm = id >> 1, p = id & 1;                                  \
                const float* g = ctxA + (size_t)(jm * 16 + l15) * DIN +        \
                                 (kc_) * 32 + q * 8 + p * 4;                   \
                gload_lds16(g, &As[buf_][jm * 512 + p * 256]);                 \
            } else {                                                           \
                int jn = id - 16;                                              \
                const _Float16* g = W16 +                                      \
                    (size_t)(n0 + jn * 16 + l15) * DIN + (kc_) * 32 + q * 8;   \
                gload_lds16(g, &Bs[buf_][jn * 512]);                           \
            }                                                                  \
        }                                                                      \
    }

    f32x4 acc[2][8];
#pragma unroll
    for (int jm = 0; jm < 2; ++jm)
#pragma unroll
        for (int jn = 0; jn < 8; ++jn) acc[jm][jn] = (f32x4){0.f, 0.f, 0.f, 0.f};

    STAGE(0, 0);

    for (int kc = 0; kc < 16; ++kc) {
        __syncthreads();                 // drains stage(kc); prior buf reads done
        int buf = kc & 1;
        if (kc + 1 < 16) STAGE(kc + 1, (kc + 1) & 1);

        // A frags for this wave's 2 m-tiles
        f16x8 afr[2];
#pragma unroll
        for (int jm = 0; jm < 2; ++jm) {
            int jma = sg * 2 + jm;
            float4 x0 = *(const float4*)&As[buf][jma * 512 + lane * 4];
            float4 x1 = *(const float4*)&As[buf][jma * 512 + 256 + lane * 4];
            f16x8 t;
            t[0] = (_Float16)x0.x; t[1] = (_Float16)x0.y;
            t[2] = (_Float16)x0.z; t[3] = (_Float16)x0.w;
            t[4] = (_Float16)x1.x; t[5] = (_Float16)x1.y;
            t[6] = (_Float16)x1.z; t[7] = (_Float16)x1.w;
            afr[jm] = t;
        }
#pragma unroll
        for (int jn = 0; jn < 8; ++jn) {
            int jna = ng * 8 + jn;
            f16x8 bf = *(const f16x8*)&Bs[buf][jna * 512 + q * 128 + l15 * 8];
            acc[0][jn] = __builtin_amdgcn_mfma_f32_16x16x32_f16(afr[0], bf, acc[0][jn], 0, 0, 0);
            acc[1][jn] = __builtin_amdgcn_mfma_f32_16x16x32_f16(afr[1], bf, acc[1][jn], 0, 0, 0);
        }
    }

    // ---- epilogue: rowsum over this wave's 128 n-cols, atomicAdd to scores ----
    const float* avb = addv + b * DH;
    float rowsum[2][4] = {{0.f,0.f,0.f,0.f},{0.f,0.f,0.f,0.f}};
#pragma unroll
    for (int jn = 0; jn < 8; ++jn) {
        int n = n0 + (ng * 8 + jn) * 16 + l15;
        float av = avb[n];
        float vv = v[n];
#pragma unroll
        for (int jm = 0; jm < 2; ++jm)
#pragma unroll
            for (int r = 0; r < 4; ++r)
                rowsum[jm][r] += vv * fast_tanh(acc[jm][jn][r] + av);
    }
#pragma unroll
    for (int jm = 0; jm < 2; ++jm)
#pragma unroll
        for (int r = 0; r < 4; ++r) {
            float s = rowsum[jm][r];
            s += __shfl_xor(s, 1, 16);
            s += __shfl_xor(s, 2, 16);
            s += __shfl_xor(s, 4, 16);
            s += __shfl_xor(s, 8, 16);
            if (l15 == 0) {
                int srow = s0 + (sg * 2 + jm) * 16 + q * 4 + r;  // C row=q*4+r
                atomicAdd(&scores[b * S_ + srow], s);
            }
        }
}

// ---------------- stats: masked max & sum per batch row ----------------
__global__ __launch_bounds__(256)
void stats_kernel(const float* __restrict__ scores,
                  const void* __restrict__ mask,
                  const int* __restrict__ maskflag,
                  float* __restrict__ stats) {
    __shared__ float rbuf[8];
    int b = blockIdx.x, tid = threadIdx.x;
    int wv = tid >> 6, ln = tid & 63;
    int isByte = maskflag[0];
    const float* sr = scores + b * S_;

    float mx = -__builtin_inff();
    float vals[16];
#pragma unroll
    for (int it = 0; it < 16; ++it) {
        int s = it * 256 + tid;
        float x = mask_at(mask, isByte, b * S_ + s) ? -__builtin_inff() : sr[s];
        vals[it] = x;
        mx = fmaxf(mx, x);
    }
    for (int o = 1; o < 64; o <<= 1) mx = fmaxf(mx, __shfl_xor(mx, o, 64));
    if (ln == 0) rbuf[wv] = mx;
    __syncthreads();
    mx = fmaxf(fmaxf(rbuf[0], rbuf[1]), fmaxf(rbuf[2], rbuf[3]));

    float sum = 0.f;
#pragma unroll
    for (int it = 0; it < 16; ++it) sum += __expf(vals[it] - mx);
    for (int o = 1; o < 64; o <<= 1) sum += __shfl_xor(sum, o, 64);
    __syncthreads();
    if (ln == 0) rbuf[4 + wv] = sum;
    __syncthreads();
    if (tid == 0) {
        sum = rbuf[4] + rbuf[5] + rbuf[6] + rbuf[7];
        stats[b * 2]     = mx;
        stats[b * 2 + 1] = 1.f / sum;
    }
}

// ---------------- attn write + sparse weighted context sum ----------------
// 256 blocks: (b, 256-row chunk). Peaked softmax -> few selected rows/chunk.
__global__ __launch_bounds__(256)
void attnwsum_kernel(const float* __restrict__ scores,
                     const float* __restrict__ context,
                     const void* __restrict__ mask,
                     const int* __restrict__ maskflag,
                     const float* __restrict__ stats,
                     float* __restrict__ attn,
                     float* __restrict__ wsum) {
    __shared__ int   selIdx[256];
    __shared__ float selW[256];
    __shared__ int   selCount;

    int b  = blockIdx.x >> 4;
    int c0 = (blockIdx.x & 15) * 256;
    int tid = threadIdx.x;
    int isByte = maskflag[0];
    float mx  = stats[b * 2];
    float inv = stats[b * 2 + 1];

    if (tid == 0) selCount = 0;
    __syncthreads();

    int s = c0 + tid;
    int idx = b * S_ + s;
    float sc = mask_at(mask, isByte, idx) ? -__builtin_inff() : scores[idx];
    float p = __expf(sc - mx) * inv;
    attn[idx] = p;
    if (p > 1e-9f) {
        int k = atomicAdd(&selCount, 1);
        selIdx[k] = s;
        selW[k]  = p;
    }
    __syncthreads();

    int cnt = selCount;
    if (cnt == 0) return;
    const float* cb = context + (size_t)b * S_ * DIN;
    float a00 = 0.f, a01 = 0.f, a10 = 0.f, a11 = 0.f;
    float a20 = 0.f, a21 = 0.f, a30 = 0.f, a31 = 0.f;
    int i = 0;
    for (; i + 4 <= cnt; i += 4) {
        const float* c0p = cb + (size_t)selIdx[i]     * DIN;
        const float* c1p = cb + (size_t)selIdx[i + 1] * DIN;
        const float* c2p = cb + (size_t)selIdx[i + 2] * DIN;
        const float* c3p = cb + (size_t)selIdx[i + 3] * DIN;
        float w0 = selW[i], w1 = selW[i + 1], w2 = selW[i + 2], w3 = selW[i + 3];
        a00 += w0 * c0p[tid]; a01 += w0 * c0p[tid + 256];
        a10 += w1 * c1p[tid]; a11 += w1 * c1p[tid + 256];
        a20 += w2 * c2p[tid]; a21 += w2 * c2p[tid + 256];
        a30 += w3 * c3p[tid]; a31 += w3 * c3p[tid + 256];
    }
    float acc0 = (a00 + a10) + (a20 + a30);
    float acc1 = (a01 + a11) + (a21 + a31);
    for (; i < cnt; ++i) {
        const float* cr = cb + (size_t)selIdx[i] * DIN;
        float w = selW[i];
        acc0 += w * cr[tid];
        acc1 += w * cr[tid + 256];
    }
    atomicAdd(&wsum[b * DIN + tid], acc0);
    atomicAdd(&wsum[b * DIN + tid + 256], acc1);
}

// ---------------- hidden = W_ctx @ wsum + b_ctx ----------------
__global__ __launch_bounds__(256)
void hidden_kernel(const float* __restrict__ W_ctx,
                   const float* __restrict__ b_ctx,
                   const float* __restrict__ wsum,
                   float* __restrict__ hidden) {
    int b = blockIdx.x >> 1;
    int tid = threadIdx.x;
    int h = ((blockIdx.x & 1) << 8) + tid;
    __shared__ float wrow[DIN];
    wrow[tid]       = wsum[b * DIN + tid];
    wrow[tid + 256] = wsum[b * DIN + tid + 256];
    __syncthreads();
    const float* wr = W_ctx + (size_t)h * DIN;
    float acc = 0.f;
    for (int k = 0; k < DIN; k += 4) {
        float4 w4 = *(const float4*)(wr + k);
        acc += w4.x * wrow[k] + w4.y * wrow[k + 1]
             + w4.z * wrow[k + 2] + w4.w * wrow[k + 3];
    }
    hidden[b * DH + h] = acc + b_ctx[h];
}

extern "C" void kernel_launch(void* const* d_in, const int* in_sizes, int n_in,
                              void* d_out, int out_size, void* d_ws, size_t ws_size,
                              hipStream_t stream) {
    const float* input   = (const float*)d_in[0];
    const float* context = (const float*)d_in[1];
    const void*  mask    = d_in[2];
    const float* W_in    = (const float*)d_in[3];
    const float* b_in    = (const float*)d_in[4];
    const float* W_ctx   = (const float*)d_in[5];
    const float* b_ctx   = (const float*)d_in[6];
    const float* v       = (const float*)d_in[7];

    char* ws = (char*)d_ws;
    _Float16* W16   = (_Float16*)ws;
    float* addv     = (float*)(ws + 524288);
    float* scores   = (float*)(ws + 557056);
    float* wsum     = (float*)(ws + 819200);
    int*   maskflag = (int*)(ws + 851968);
    float* stats    = (float*)(ws + 852096);

    float* hidden = (float*)d_out;                  // [16,512]
    float* attn   = (float*)d_out + B_ * DH;        // [16,4096]

    prep_kernel<<<355, 256, 0, stream>>>(input, W_in, b_in, W_ctx, b_ctx, mask,
                                         W16, addv, scores /*zero region*/, maskflag);
    score_kernel<<<1024, 512, 0, stream>>>(context, W16, addv, v, scores);
    stats_kernel<<<B_, 256, 0, stream>>>(scores, mask, maskflag, stats);
    attnwsum_kernel<<<B_ * 16, 256, 0, stream>>>(scores, context, mask, maskflag,
                                                 stats, attn, wsum);
    hidden_kernel<<<B_ * 2, 256, 0, stream>>>(W_ctx, b_ctx, wsum, hidden);
}